// Round 7
// baseline (6638.277 us; speedup 1.0000x reference)
//
#include <hip/hip_runtime.h>
#include <hip/hip_bf16.h>
#include <math.h>

#define RNN_B    256
#define RNN_T    512
#define RNN_DIN  512
#define RNN_DH   1024
#define RNN_DOUT 512
#define RNN_K    (RNN_DIN + RNN_DH)   // 1536

#define NGRP 16          // batch groups (16 rows each)
#define MR   16          // batch rows per group
#define NBLK 16          // col-blocks per group
#define NC   64          // h cols per block (4 waves x 16)

typedef __bf16 bf16x8 __attribute__((ext_vector_type(8)));
typedef float  f32x4  __attribute__((ext_vector_type(4)));
typedef unsigned long long u64;

static __device__ __forceinline__ bf16x8 ld_bf8(const __hip_bfloat16* p) {
  return *reinterpret_cast<const bf16x8*>(p);
}

static __device__ __forceinline__ bf16x8 ld_f32_as_bf8(const float* p) {
  const float4* q = reinterpret_cast<const float4*>(p);
  float4 u = q[0], v = q[1];
  bf16x8 r;
  r[0] = (__bf16)u.x; r[1] = (__bf16)u.y; r[2] = (__bf16)u.z; r[3] = (__bf16)u.w;
  r[4] = (__bf16)v.x; r[5] = (__bf16)v.y; r[6] = (__bf16)v.z; r[7] = (__bf16)v.w;
  return r;
}

// ---- fp32 -> bf16 cast ----
__global__ void cast_f32_to_bf16(const float* __restrict__ src,
                                 unsigned long long* __restrict__ dst,
                                 int n4) {
  int i = blockIdx.x * blockDim.x + threadIdx.x;
  const int stride = gridDim.x * blockDim.x;
  for (; i < n4; i += stride) {
    float4 v = reinterpret_cast<const float4*>(src)[i];
    unsigned long long w =
        (unsigned long long)__builtin_bit_cast(unsigned short, (__bf16)v.x)
      | ((unsigned long long)__builtin_bit_cast(unsigned short, (__bf16)v.y) << 16)
      | ((unsigned long long)__builtin_bit_cast(unsigned short, (__bf16)v.z) << 32)
      | ((unsigned long long)__builtin_bit_cast(unsigned short, (__bf16)v.w) << 48);
    dst[i] = w;
  }
}

// x-part GEMM for step t (k = 0..511): no h dependency -> off the critical path
template<bool USE_XBF>
static __device__ __forceinline__ void xpart(const __hip_bfloat16* xbf, const float* xf,
                                             int m0, int lm, int lk, int t,
                                             const uint4* Wreg, f32x4* acc) {
#pragma unroll
  for (int i = 0; i < 4; ++i) acc[i] = (f32x4){0.f, 0.f, 0.f, 0.f};
  if constexpr (USE_XBF) {
    const __hip_bfloat16* xb = xbf + ((size_t)(m0 + lm) * RNN_T + (t - 1)) * RNN_DIN + lk;
#pragma unroll
    for (int s = 0; s < 16; ++s) {
      bf16x8 a = ld_bf8(xb + s * 32);
      acc[s & 3] = __builtin_amdgcn_mfma_f32_16x16x32_bf16(
          a, __builtin_bit_cast(bf16x8, Wreg[s]), acc[s & 3], 0, 0, 0);
    }
  } else {
    const float* xb = xf + ((size_t)(m0 + lm) * RNN_T + (t - 1)) * RNN_DIN + lk;
#pragma unroll
    for (int s = 0; s < 16; ++s) {
      bf16x8 a = ld_f32_as_bf8(xb + s * 32);
      acc[s & 3] = __builtin_amdgcn_mfma_f32_16x16x32_bf16(
          a, __builtin_bit_cast(bf16x8, Wreg[s]), acc[s & 3], 0, 0, 0);
    }
  }
}

// ---- sequential scan: 256 blocks = 16 groups x 16 col-blocks ----
// R3-PROVEN protocol: normal cached h loads/stores; producer RELEASE fetch_add
// (s_waitcnt + buffer_wbl2 + atomic) publishes h; consumer ACQUIRE load
// (+ buffer_inv) makes it visible. ONLY change vs R3: W is pinned in VGPRs via
// per-component scalar asm ties -> the per-step W re-fetch (the 6.6ms cost,
// R3 VGPR=128 evidence) is structurally impossible.
template<bool USE_XBF>
__launch_bounds__(256, 1)
__global__ void rnn_scan(const __hip_bfloat16* __restrict__ xbf,  // [B][T][DIN] bf16
                         const float* __restrict__ xf,            // fp32 fallback
                         const __hip_bfloat16* __restrict__ Wbf,  // [DH][K] bf16
                         const float* __restrict__ bfc,           // [DH]
                         __hip_bfloat16* hbuf,                    // [2][B][DH] bf16
                         unsigned int* flags,                     // [NGRP][T+1]
                         float* __restrict__ outh)                // [B][DH] fp32
{
  const int bid = blockIdx.x;
  const int g = bid >> 4;        // batch group
  const int c = bid & 15;        // col block within group
  const int tid = threadIdx.x;
  const int w  = tid >> 6;
  const int l  = tid & 63;
  const int lm = l & 15;
  const int lk = (l >> 4) * 8;
  const int m0 = g * MR;
  const int nw = c * NC + w * 16;    // this wave's col base

  __shared__ uint4 hls[MR * 129];    // 16 rows x 128 uint4 + 1 pad -> 33KB

  // ---- W fragments: load once, PIN in VGPRs (scalar-component asm ties,
  // compile-proven in R5/R6; values opaque -> no rematerialization)
  uint4 Wreg[48];
  {
    const __hip_bfloat16* wr = Wbf + (size_t)(nw + lm) * RNN_K + lk;
#pragma unroll
    for (int s = 0; s < 48; ++s) Wreg[s] = *reinterpret_cast<const uint4*>(wr + s * 32);
#pragma unroll
    for (int s = 0; s < 48; ++s)
      asm volatile("" : "+v"(Wreg[s].x), "+v"(Wreg[s].y),
                        "+v"(Wreg[s].z), "+v"(Wreg[s].w));
  }
  const float bv = bfc[nw + lm];     // bias for this lane's output col
  const int rr = (l >> 4) * 4;       // C-frag row base (m89-verified layout)
  unsigned int* myflags = flags + g * (RNN_T + 1);

  f32x4 acc[4];
  xpart<USE_XBF>(xbf, xf, m0, lm, lk, 1, Wreg, acc);

  for (int t = 1; t <= RNN_T; ++t) {
    if (t > 1) {
      if (tid == 0) {
        unsigned int* fp = myflags + (t - 1);
        int it = 0;
        while (__hip_atomic_load(fp, __ATOMIC_RELAXED, __HIP_MEMORY_SCOPE_AGENT)
               < (unsigned)NBLK) {
          __builtin_amdgcn_s_sleep(1);
          if (++it > 4000000) break;   // fail visibly, never hang
        }
        (void)__hip_atomic_load(fp, __ATOMIC_ACQUIRE, __HIP_MEMORY_SCOPE_AGENT);
      }
      __syncthreads();
    }

    // ---- stage h(t-1) rows [m0, m0+16): 32KB global -> LDS (normal cached loads)
    {
      const uint4* hsrc = (const uint4*)hbuf + (size_t)((t - 1) & 1) * 32768
                          + (size_t)m0 * 128;
      uint4 stg[8];
#pragma unroll
      for (int j = 0; j < 8; ++j) stg[j] = hsrc[j * 256 + tid];
#pragma unroll
      for (int j = 0; j < 8; ++j) {
        int idx = j * 256 + tid;
        hls[idx + (idx >> 7)] = stg[j];
      }
    }
    __syncthreads();

    // ---- h-part MFMAs (k = 512..1535) from LDS (W pinned in VGPRs)
#pragma unroll
    for (int ks = 0; ks < 32; ++ks) {
      const bf16x8 a = *reinterpret_cast<const bf16x8*>(
          &hls[lm * 129 + ks * 4 + (l >> 4)]);
      acc[ks & 3] = __builtin_amdgcn_mfma_f32_16x16x32_bf16(
          a, __builtin_bit_cast(bf16x8, Wreg[16 + ks]), acc[ks & 3], 0, 0, 0);
    }

    // ---- epilogue: bias + tanh, normal h store (wbl2 at release publishes it)
    unsigned short* hdu = (unsigned short*)(hbuf + (size_t)(t & 1) * (RNN_B * RNN_DH));
#pragma unroll
    for (int q = 0; q < 4; ++q) {
      float s = acc[0][q] + acc[1][q] + acc[2][q] + acc[3][q] + bv;
      float e  = __expf(-2.0f * fabsf(s));
      float th = (1.0f - e) * __builtin_amdgcn_rcpf(1.0f + e);
      float v  = copysignf(th, s);
      hdu[(size_t)(m0 + rr + q) * RNN_DH + nw + lm] =
          __builtin_bit_cast(unsigned short, (__bf16)v);
      if (t == RNN_T) outh[(size_t)(m0 + rr + q) * RNN_DH + nw + lm] = v;
    }
    asm volatile("s_waitcnt vmcnt(0)" ::: "memory");
    __syncthreads();

    if (tid == 0)
      __hip_atomic_fetch_add(myflags + t, 1u,
                             __ATOMIC_RELEASE, __HIP_MEMORY_SCOPE_AGENT);

    // ---- prefetch-compute x-part of step t+1 while peers finish step t
    if (t < RNN_T) xpart<USE_XBF>(xbf, xf, m0, lm, lk, t + 1, Wreg, acc);
  }
}

// ---- y = h_final @ W_out^T + b_out via MFMA (bf16 inputs) ----
__global__ void out_gemm_mfma(const __hip_bfloat16* __restrict__ hfin,  // [B][DH] bf16
                              const __hip_bfloat16* __restrict__ Wob,   // [DOUT][DH] bf16
                              const float* __restrict__ bout,           // [DOUT]
                              float* __restrict__ y)                    // [B][DOUT]
{
  const int mi = blockIdx.x >> 3;
  const int ni = blockIdx.x & 7;
  const int w = threadIdx.x >> 6, l = threadIdx.x & 63;
  const int lm = l & 15, lk = (l >> 4) * 8;
  const int row0 = mi * 64 + w * 16;
  const int col0 = ni * 64;

  f32x4 acc[4];
#pragma unroll
  for (int i = 0; i < 4; ++i) acc[i] = (f32x4){0.f, 0.f, 0.f, 0.f};

#pragma unroll 4
  for (int ks = 0; ks < 32; ++ks) {
    bf16x8 a = ld_bf8(hfin + (size_t)(row0 + lm) * RNN_DH + ks * 32 + lk);
#pragma unroll
    for (int nf = 0; nf < 4; ++nf) {
      bf16x8 b = ld_bf8(Wob + (size_t)(col0 + nf * 16 + lm) * RNN_DH + ks * 32 + lk);
      acc[nf] = __builtin_amdgcn_mfma_f32_16x16x32_bf16(a, b, acc[nf], 0, 0, 0);
    }
  }
  const int rr = (l >> 4) * 4;
#pragma unroll
  for (int nf = 0; nf < 4; ++nf)
#pragma unroll
    for (int q = 0; q < 4; ++q)
      y[(size_t)(row0 + rr + q) * RNN_DOUT + col0 + nf * 16 + lm] =
          acc[nf][q] + bout[col0 + nf * 16 + lm];
}

// fp32 fallback out-GEMM (if ws too small for Wout bf16 copy)
__global__ void out_gemm(const float* __restrict__ hfin, const float* __restrict__ Wout,
                         const float* __restrict__ bout, float* __restrict__ y) {
  __shared__ float hs[RNN_DH];
  const int b = blockIdx.x;
  for (int j = threadIdx.x; j < RNN_DH; j += 256)
    hs[j] = hfin[(size_t)b * RNN_DH + j];
  __syncthreads();
  for (int o = threadIdx.x; o < RNN_DOUT; o += 256) {
    const float4* wr = reinterpret_cast<const float4*>(Wout + (size_t)o * RNN_DH);
    float acc = 0.f;
#pragma unroll 4
    for (int k4 = 0; k4 < RNN_DH / 4; ++k4) {
      float4 wv = wr[k4];
      acc += hs[4*k4] * wv.x + hs[4*k4+1] * wv.y + hs[4*k4+2] * wv.z + hs[4*k4+3] * wv.w;
    }
    y[(size_t)b * RNN_DOUT + o] = acc + bout[o];
  }
}

extern "C" void kernel_launch(void* const* d_in, const int* in_sizes, int n_in,
                              void* d_out, int out_size, void* d_ws, size_t ws_size,
                              hipStream_t stream) {
  const float* x    = (const float*)d_in[0];
  const float* h0   = (const float*)d_in[1];
  const float* Wfc  = (const float*)d_in[2];
  const float* bfc  = (const float*)d_in[3];
  const float* Wout = (const float*)d_in[4];
  const float* bout = (const float*)d_in[5];

  float* y    = (float*)d_out;                         // [B][DOUT]
  float* outh = y + (size_t)RNN_B * RNN_DOUT;          // [B][DH]

  // ws layout: [hbuf 1MB][flags 64KB][Wbf 3MB][Woutbf 1MB][xbf 128MB]
  char* p = (char*)d_ws;
  __hip_bfloat16* hbuf = (__hip_bfloat16*)p;  p += (size_t)2 * RNN_B * RNN_DH * 2;
  unsigned int*   flags = (unsigned int*)p;   p += 65536;
  __hip_bfloat16* Wbf  = (__hip_bfloat16*)p;  p += (size_t)RNN_DH * RNN_K * 2;
  __hip_bfloat16* Wob  = (__hip_bfloat16*)p;
  const size_t need_wob = (size_t)(p - (char*)d_ws) + (size_t)RNN_DOUT * RNN_DH * 2;
  p += (size_t)RNN_DOUT * RNN_DH * 2;
  __hip_bfloat16* xbf  = (__hip_bfloat16*)p;
  const size_t need_xbf = (size_t)(p - (char*)d_ws) + (size_t)RNN_B * RNN_T * RNN_DIN * 2;
  const bool use_wob = (ws_size >= need_wob);
  const bool use_xbf = (ws_size >= need_xbf);

  hipMemsetAsync(flags, 0, NGRP * (RNN_T + 1) * sizeof(unsigned int), stream);

  cast_f32_to_bf16<<<dim3(1024), dim3(256), 0, stream>>>(
      Wfc, (unsigned long long*)Wbf, RNN_DH * RNN_K / 4);
  cast_f32_to_bf16<<<dim3(256), dim3(256), 0, stream>>>(
      h0, (unsigned long long*)hbuf, RNN_B * RNN_DH / 4);
  if (use_wob)
    cast_f32_to_bf16<<<dim3(256), dim3(256), 0, stream>>>(
        Wout, (unsigned long long*)Wob, RNN_DOUT * RNN_DH / 4);
  if (use_xbf)
    cast_f32_to_bf16<<<dim3(2048), dim3(256), 0, stream>>>(
        x, (unsigned long long*)xbf, RNN_B * RNN_T * RNN_DIN / 4);

  void* kargs[] = { (void*)&xbf, (void*)&x, (void*)&Wbf, (void*)&bfc,
                    (void*)&hbuf, (void*)&flags, (void*)&outh };
  if (use_xbf) {
    hipLaunchCooperativeKernel((const void*)&rnn_scan<true>,
                               dim3(256), dim3(256), kargs, 0, stream);
  } else {
    hipLaunchCooperativeKernel((const void*)&rnn_scan<false>,
                               dim3(256), dim3(256), kargs, 0, stream);
  }

  // h_final (bf16) is hbuf buffer (T&1)==0 -> hbuf base
  if (use_wob) {
    out_gemm_mfma<<<dim3(32), dim3(256), 0, stream>>>(hbuf, Wob, bout, y);
  } else {
    out_gemm<<<dim3(256), dim3(256), 0, stream>>>(outh, Wout, bout, y);
  }
}

// Round 9
// 3203.970 us; speedup vs baseline: 2.0719x; 2.0719x over previous
//
#include <hip/hip_runtime.h>
#include <hip/hip_bf16.h>
#include <math.h>

#define RNN_B    256
#define RNN_T    512
#define RNN_DIN  512
#define RNN_DH   1024
#define RNN_DOUT 512
#define RNN_K    (RNN_DIN + RNN_DH)   // 1536

#define NGRP 16          // batch groups (16 rows each)
#define MR   16          // batch rows per group
#define NBLK 16          // col-blocks per group
#define NC   64          // h cols per block (4 waves x 16)

typedef __bf16 bf16x8 __attribute__((ext_vector_type(8)));
typedef float  f32x4  __attribute__((ext_vector_type(4)));
typedef unsigned long long u64;
typedef unsigned int u32;
typedef unsigned short u16;

static __device__ __forceinline__ bf16x8 ld_bf8(const __hip_bfloat16* p) {
  return *reinterpret_cast<const bf16x8*>(p);
}

static __device__ __forceinline__ bf16x8 ld_f32_as_bf8(const float* p) {
  const float4* q = reinterpret_cast<const float4*>(p);
  float4 u = q[0], v = q[1];
  bf16x8 r;
  r[0] = (__bf16)u.x; r[1] = (__bf16)u.y; r[2] = (__bf16)u.z; r[3] = (__bf16)u.w;
  r[4] = (__bf16)v.x; r[5] = (__bf16)v.y; r[6] = (__bf16)v.z; r[7] = (__bf16)v.w;
  return r;
}

// ---- fp32 -> bf16 cast ----
__global__ void cast_f32_to_bf16(const float* __restrict__ src,
                                 unsigned long long* __restrict__ dst,
                                 int n4) {
  int i = blockIdx.x * blockDim.x + threadIdx.x;
  const int stride = gridDim.x * blockDim.x;
  for (; i < n4; i += stride) {
    float4 v = reinterpret_cast<const float4*>(src)[i];
    unsigned long long w =
        (unsigned long long)__builtin_bit_cast(unsigned short, (__bf16)v.x)
      | ((unsigned long long)__builtin_bit_cast(unsigned short, (__bf16)v.y) << 16)
      | ((unsigned long long)__builtin_bit_cast(unsigned short, (__bf16)v.z) << 32)
      | ((unsigned long long)__builtin_bit_cast(unsigned short, (__bf16)v.w) << 48);
    dst[i] = w;
  }
}

// x-part GEMM for step t (k = 0..511): no h dependency -> off the critical path.
// W read via normal cached loads (never invalidated -> L1/L2-hot).
template<bool USE_XBF>
static __device__ __forceinline__ void xpart(const __hip_bfloat16* xbf, const float* xf,
                                             const __hip_bfloat16* Wbf,
                                             int m0, int nw, int lm, int lk, int t,
                                             f32x4* acc) {
#pragma unroll
  for (int i = 0; i < 4; ++i) acc[i] = (f32x4){0.f, 0.f, 0.f, 0.f};
  const __hip_bfloat16* Wr = Wbf + (size_t)(nw + lm) * RNN_K + lk;
  if constexpr (USE_XBF) {
    const __hip_bfloat16* xb = xbf + ((size_t)(m0 + lm) * RNN_T + (t - 1)) * RNN_DIN + lk;
#pragma unroll
    for (int s = 0; s < 16; ++s) {
      bf16x8 a = ld_bf8(xb + s * 32);
      bf16x8 b = ld_bf8(Wr + s * 32);
      acc[s & 3] = __builtin_amdgcn_mfma_f32_16x16x32_bf16(a, b, acc[s & 3], 0, 0, 0);
    }
  } else {
    const float* xb = xf + ((size_t)(m0 + lm) * RNN_T + (t - 1)) * RNN_DIN + lk;
#pragma unroll
    for (int s = 0; s < 16; ++s) {
      bf16x8 a = ld_f32_as_bf8(xb + s * 32);
      bf16x8 b = ld_bf8(Wr + s * 32);
      acc[s & 3] = __builtin_amdgcn_mfma_f32_16x16x32_bf16(a, b, acc[s & 3], 0, 0, 0);
    }
  }
}

// ---- sequential scan: 256 blocks = 16 groups x 16 col-blocks ----
// h exchange uses the PROVEN u32 atomic channel (the exact ops the flag
// mechanism has used successfully in every round, R1-R8):
//   produce: u32 global_atomic_swap (returning) -> vmcnt(0) -> flag fetch_add
//   consume: u32 relaxed agent atomic loads
// NO buffer_wbl2 / buffer_inv anywhere -> W and x stay hot in L1/L2.
template<bool USE_XBF>
__launch_bounds__(256, 1)
__global__ void rnn_scan(const __hip_bfloat16* __restrict__ xbf,  // [B][T][DIN] bf16
                         const float* __restrict__ xf,            // fp32 fallback
                         const __hip_bfloat16* __restrict__ Wbf,  // [DH][K] bf16
                         const float* __restrict__ bfc,           // [DH]
                         u32* hbuf32,                             // [2][B][DH/2] u32(bf16x2)
                         unsigned int* flags,                     // [NGRP][T+1]
                         float* __restrict__ outh)                // [B][DH] fp32
{
  const int bid = blockIdx.x;
  const int g = bid >> 4;        // batch group
  const int c = bid & 15;        // col block within group
  const int tid = threadIdx.x;
  const int w  = tid >> 6;
  const int l  = tid & 63;
  const int lm = l & 15;
  const int lk = (l >> 4) * 8;
  const int m0 = g * MR;
  const int nw = c * NC + w * 16;    // this wave's col base

  __shared__ __align__(16) u32 hls[MR * 516];   // 33KB staged h_prev (2-way banks)
  __shared__ __align__(16) u16 ots[16 * 68];    // 2.1KB output transpose tile

  const float bv = bfc[nw + lm];     // bias for this lane's output col
  const int rr = (l >> 4) * 4;       // C-frag row base (m89-verified layout)
  unsigned int* myflags = flags + g * (RNN_T + 1);
  const __hip_bfloat16* Wrh = Wbf + (size_t)(nw + lm) * RNN_K + RNN_DIN + lk;

  f32x4 acc[4];
  xpart<USE_XBF>(xbf, xf, Wbf, m0, nw, lm, lk, 1, acc);

  for (int t = 1; t <= RNN_T; ++t) {
    if (t > 1) {
      if (tid == 0) {
        unsigned int* fp = myflags + (t - 1);
        int it = 0;
        while (__hip_atomic_load(fp, __ATOMIC_RELAXED, __HIP_MEMORY_SCOPE_AGENT)
               < (unsigned)NBLK) {
          __builtin_amdgcn_s_sleep(1);
          if (++it > 4000000) break;   // fail visibly, never hang
        }
      }
      __syncthreads();   // (A)
    }

    // ---- stage h(t-1) rows [m0, m0+16): 32KB = 8192 u32 coherent atomic loads
    {
      const u32* hsrc = hbuf32 + (size_t)((t - 1) & 1) * 131072 + (size_t)m0 * 512;
      u32 stg[32];
#pragma unroll
      for (int i = 0; i < 32; ++i)
        stg[i] = __hip_atomic_load(hsrc + i * 256 + tid,
                                   __ATOMIC_RELAXED, __HIP_MEMORY_SCOPE_AGENT);
#pragma unroll
      for (int i = 0; i < 32; ++i) {
        const int n = i * 256 + tid;
        hls[(n >> 9) * 516 + (n & 511)] = stg[i];
      }
    }
    __syncthreads();   // (B)

    // ---- h-part MFMAs (k = 512..1535): A from LDS, B (W) from L2-hot global
#pragma unroll
    for (int ks = 0; ks < 32; ++ks) {
      const bf16x8 a = *reinterpret_cast<const bf16x8*>(
          &hls[lm * 516 + ks * 16 + (l >> 4) * 4]);
      const bf16x8 b = ld_bf8(Wrh + ks * 32);
      acc[ks & 3] = __builtin_amdgcn_mfma_f32_16x16x32_bf16(a, b, acc[ks & 3], 0, 0, 0);
    }

    // ---- epilogue: bias + tanh -> LDS transpose tile (16 rows x 64 cols)
#pragma unroll
    for (int q = 0; q < 4; ++q) {
      float s = acc[0][q] + acc[1][q] + acc[2][q] + acc[3][q] + bv;
      float e  = __expf(-2.0f * fabsf(s));
      float th = (1.0f - e) * __builtin_amdgcn_rcpf(1.0f + e);
      float v  = copysignf(th, s);
      ots[(rr + q) * 68 + w * 16 + lm] = __builtin_bit_cast(u16, (__bf16)v);
      if (t == RNN_T) outh[(size_t)(m0 + rr + q) * RNN_DH + nw + lm] = v;
    }
    __syncthreads();   // (C)

    // ---- publish: 2 u32 atomic exchanges per thread (proven RMW channel).
    // Returning variant (results consumed) -> vmcnt(0) = committed at the
    // coherent point before the flag RMW issues.
    {
      const u32* ots32 = reinterpret_cast<const u32*>(ots);   // row stride 34
      const int i = tid >> 4, j0 = (tid & 15) * 2;
      u32 v0 = ots32[i * 34 + j0];
      u32 v1 = ots32[i * 34 + j0 + 1];
      u32* hdst = hbuf32 + (size_t)(t & 1) * 131072 + (size_t)(m0 + i) * 512 + c * 32;
      u32 r0 = __hip_atomic_exchange(hdst + j0,     v0,
                                     __ATOMIC_RELAXED, __HIP_MEMORY_SCOPE_AGENT);
      u32 r1 = __hip_atomic_exchange(hdst + j0 + 1, v1,
                                     __ATOMIC_RELAXED, __HIP_MEMORY_SCOPE_AGENT);
      asm volatile("" :: "v"(r0), "v"(r1));   // keep the returning form
    }
    asm volatile("s_waitcnt vmcnt(0)" ::: "memory");
    __syncthreads();   // (D) whole block's h is at the coherent point

    if (tid == 0)
      __hip_atomic_fetch_add(myflags + t, 1u,
                             __ATOMIC_RELAXED, __HIP_MEMORY_SCOPE_AGENT);

    // ---- prefetch-compute x-part of step t+1 while peers finish step t
    if (t < RNN_T) xpart<USE_XBF>(xbf, xf, Wbf, m0, nw, lm, lk, t + 1, acc);
  }
}

// ---- y = h_final @ W_out^T + b_out via MFMA (bf16 inputs) ----
__global__ void out_gemm_mfma(const __hip_bfloat16* __restrict__ hfin,  // [B][DH] bf16
                              const __hip_bfloat16* __restrict__ Wob,   // [DOUT][DH] bf16
                              const float* __restrict__ bout,           // [DOUT]
                              float* __restrict__ y)                    // [B][DOUT]
{
  const int mi = blockIdx.x >> 3;
  const int ni = blockIdx.x & 7;
  const int w = threadIdx.x >> 6, l = threadIdx.x & 63;
  const int lm = l & 15, lk = (l >> 4) * 8;
  const int row0 = mi * 64 + w * 16;
  const int col0 = ni * 64;

  f32x4 acc[4];
#pragma unroll
  for (int i = 0; i < 4; ++i) acc[i] = (f32x4){0.f, 0.f, 0.f, 0.f};

#pragma unroll 4
  for (int ks = 0; ks < 32; ++ks) {
    bf16x8 a = ld_bf8(hfin + (size_t)(row0 + lm) * RNN_DH + ks * 32 + lk);
#pragma unroll
    for (int nf = 0; nf < 4; ++nf) {
      bf16x8 b = ld_bf8(Wob + (size_t)(col0 + nf * 16 + lm) * RNN_DH + ks * 32 + lk);
      acc[nf] = __builtin_amdgcn_mfma_f32_16x16x32_bf16(a, b, acc[nf], 0, 0, 0);
    }
  }
  const int rr = (l >> 4) * 4;
#pragma unroll
  for (int nf = 0; nf < 4; ++nf)
#pragma unroll
    for (int q = 0; q < 4; ++q)
      y[(size_t)(row0 + rr + q) * RNN_DOUT + col0 + nf * 16 + lm] =
          acc[nf][q] + bout[col0 + nf * 16 + lm];
}

// fp32 fallback out-GEMM (if ws too small for Wout bf16 copy)
__global__ void out_gemm(const float* __restrict__ hfin, const float* __restrict__ Wout,
                         const float* __restrict__ bout, float* __restrict__ y) {
  __shared__ float hs[RNN_DH];
  const int b = blockIdx.x;
  for (int j = threadIdx.x; j < RNN_DH; j += 256)
    hs[j] = hfin[(size_t)b * RNN_DH + j];
  __syncthreads();
  for (int o = threadIdx.x; o < RNN_DOUT; o += 256) {
    const float4* wr = reinterpret_cast<const float4*>(Wout + (size_t)o * RNN_DH);
    float acc = 0.f;
#pragma unroll 4
    for (int k4 = 0; k4 < RNN_DH / 4; ++k4) {
      float4 wv = wr[k4];
      acc += hs[4*k4] * wv.x + hs[4*k4+1] * wv.y + hs[4*k4+2] * wv.z + hs[4*k4+3] * wv.w;
    }
    y[(size_t)b * RNN_DOUT + o] = acc + bout[o];
  }
}

extern "C" void kernel_launch(void* const* d_in, const int* in_sizes, int n_in,
                              void* d_out, int out_size, void* d_ws, size_t ws_size,
                              hipStream_t stream) {
  const float* x    = (const float*)d_in[0];
  const float* h0   = (const float*)d_in[1];
  const float* Wfc  = (const float*)d_in[2];
  const float* bfc  = (const float*)d_in[3];
  const float* Wout = (const float*)d_in[4];
  const float* bout = (const float*)d_in[5];

  float* y    = (float*)d_out;                         // [B][DOUT]
  float* outh = y + (size_t)RNN_B * RNN_DOUT;          // [B][DH]

  // ws layout: [hbuf 1MB][flags 64KB][Wbf 3MB][Woutbf 1MB][xbf 128MB]
  char* p = (char*)d_ws;
  __hip_bfloat16* hbuf = (__hip_bfloat16*)p;  p += (size_t)2 * RNN_B * RNN_DH * 2;
  unsigned int*   flags = (unsigned int*)p;   p += 65536;
  __hip_bfloat16* Wbf  = (__hip_bfloat16*)p;  p += (size_t)RNN_DH * RNN_K * 2;
  __hip_bfloat16* Wob  = (__hip_bfloat16*)p;
  const size_t need_wob = (size_t)(p - (char*)d_ws) + (size_t)RNN_DOUT * RNN_DH * 2;
  p += (size_t)RNN_DOUT * RNN_DH * 2;
  __hip_bfloat16* xbf  = (__hip_bfloat16*)p;
  const size_t need_xbf = (size_t)(p - (char*)d_ws) + (size_t)RNN_B * RNN_T * RNN_DIN * 2;
  const bool use_wob = (ws_size >= need_wob);
  const bool use_xbf = (ws_size >= need_xbf);

  hipMemsetAsync(flags, 0, NGRP * (RNN_T + 1) * sizeof(unsigned int), stream);

  cast_f32_to_bf16<<<dim3(1024), dim3(256), 0, stream>>>(
      Wfc, (unsigned long long*)Wbf, RNN_DH * RNN_K / 4);
  cast_f32_to_bf16<<<dim3(256), dim3(256), 0, stream>>>(
      h0, (unsigned long long*)hbuf, RNN_B * RNN_DH / 4);
  if (use_wob)
    cast_f32_to_bf16<<<dim3(256), dim3(256), 0, stream>>>(
        Wout, (unsigned long long*)Wob, RNN_DOUT * RNN_DH / 4);
  if (use_xbf)
    cast_f32_to_bf16<<<dim3(2048), dim3(256), 0, stream>>>(
        x, (unsigned long long*)xbf, RNN_B * RNN_T * RNN_DIN / 4);

  u32* hbuf32 = (u32*)hbuf;
  void* kargs[] = { (void*)&xbf, (void*)&x, (void*)&Wbf, (void*)&bfc,
                    (void*)&hbuf32, (void*)&flags, (void*)&outh };
  if (use_xbf) {
    hipLaunchCooperativeKernel((const void*)&rnn_scan<true>,
                               dim3(256), dim3(256), kargs, 0, stream);
  } else {
    hipLaunchCooperativeKernel((const void*)&rnn_scan<false>,
                               dim3(256), dim3(256), kargs, 0, stream);
  }

  // h_final (bf16) is hbuf buffer (T&1)==0 -> hbuf base
  if (use_wob) {
    out_gemm_mfma<<<dim3(32), dim3(256), 0, stream>>>(hbuf, Wob, bout, y);
  } else {
    out_gemm<<<dim3(256), dim3(256), 0, stream>>>(outh, Wout, bout, y);
  }
}